// Round 5
// baseline (281.269 us; speedup 1.0000x reference)
//
#include <hip/hip_runtime.h>
#include <math.h>

#define NTOK 16384
#define DIM 2048
#define NEXP 64
#define TB 16              // tokens per block; wave w = expert tile 16w..16w+15
#define KC 32              // k per chunk = one MFMA K
#define NSTAGE (DIM / KC)  // 64

// flat output offsets (return order)
#define OFF_W    0
#define OFF_I    32768
#define OFF_P    65536
#define OFF_ENT  1114112
#define OFF_CONF 1114113
#define OFF_UTIL 1114114

typedef short s16x8 __attribute__((ext_vector_type(8)));
typedef float f32x4 __attribute__((ext_vector_type(4)));

__device__ __forceinline__ unsigned short f2bf(float v) {
    unsigned u = __builtin_bit_cast(unsigned, v);
    u = u + 0x7FFFu + ((u >> 16) & 1u);          // RNE
    return (unsigned short)(u >> 16);
}
__device__ __forceinline__ float bf2f(unsigned short b) {
    return __builtin_bit_cast(float, (unsigned)b << 16);
}

__global__ void router_init(float* __restrict__ out) {
    int tid = threadIdx.x;
    if (tid < 66) out[OFF_ENT + tid] = 0.0f;
}

// Split W into 3 bf16 planes (hi/mid/lo), fragment-linear:
// plane p, chunk c, ntile nt, lane l -> uint4 at wsp[p*16384 + c*256 + nt*64 + l]
// fragment element j: W[16nt + (l&15)][32c + 8*(l>>4) + j]   (verified round 4)
__global__ void router_wsplit(const float* __restrict__ Wg, uint4* __restrict__ wsp) {
    const int c = blockIdx.x;
    const int t = threadIdx.x;
    const int nt = t >> 6, l = t & 63;
    const int e  = 16 * nt + (l & 15);
    const int k0 = 32 * c + 8 * (l >> 4);
    const float* src = Wg + (size_t)e * DIM + k0;
    float4 a = *(const float4*)src;
    float4 b = *(const float4*)(src + 4);
    float v[8] = {a.x, a.y, a.z, a.w, b.x, b.y, b.z, b.w};
    unsigned short H[8], M[8], L[8];
    #pragma unroll
    for (int j = 0; j < 8; ++j) {
        H[j] = f2bf(v[j]);  float r = v[j] - bf2f(H[j]);
        M[j] = f2bf(r);     r = r - bf2f(M[j]);
        L[j] = f2bf(r);
    }
    uint4 ph, pm, pl;
    ph.x = H[0] | ((unsigned)H[1] << 16); ph.y = H[2] | ((unsigned)H[3] << 16);
    ph.z = H[4] | ((unsigned)H[5] << 16); ph.w = H[6] | ((unsigned)H[7] << 16);
    pm.x = M[0] | ((unsigned)M[1] << 16); pm.y = M[2] | ((unsigned)M[3] << 16);
    pm.z = M[4] | ((unsigned)M[5] << 16); pm.w = M[6] | ((unsigned)M[7] << 16);
    pl.x = L[0] | ((unsigned)L[1] << 16); pl.y = L[2] | ((unsigned)L[3] << 16);
    pl.z = L[4] | ((unsigned)L[5] << 16); pl.w = L[6] | ((unsigned)L[7] << 16);
    const int idx = c * 256 + t;
    wsp[idx]         = ph;
    wsp[16384 + idx] = pm;
    wsp[32768 + idx] = pl;
}

#define LOADX(p_, c_) { xset##p_[0] = xq[8*(c_) + 2*qd]; xset##p_[1] = xq[8*(c_) + 2*qd + 1]; }
#define LOADW(p_, c_) { const int idx_ = (c_)*256 + wv*64 + l;  \
                        wset##p_[0] = wq[idx_];                 \
                        wset##p_[1] = wq[16384 + idx_];         \
                        wset##p_[2] = wq[32768 + idx_]; }

// exact truncation split: v = hi + mid + lo to 24 mantissa bits, ~6 inst/elem
#define CONVX(p_) {                                                      \
    float xv[8];                                                         \
    xv[0]=xset##p_[0].x; xv[1]=xset##p_[0].y; xv[2]=xset##p_[0].z; xv[3]=xset##p_[0].w; \
    xv[4]=xset##p_[1].x; xv[5]=xset##p_[1].y; xv[6]=xset##p_[1].z; xv[7]=xset##p_[1].w; \
    _Pragma("unroll")                                                    \
    for (int j = 0; j < 8; ++j) {                                        \
        unsigned u_  = __builtin_bit_cast(unsigned, xv[j]);              \
        unsigned hb_ = u_ & 0xFFFF0000u;                                 \
        float    r_  = xv[j] - __builtin_bit_cast(float, hb_);           \
        unsigned mb_ = __builtin_bit_cast(unsigned, r_) & 0xFFFF0000u;   \
        float    r2_ = r_ - __builtin_bit_cast(float, mb_);              \
        unsigned lb_ = __builtin_bit_cast(unsigned, r2_);                \
        ah[j] = (short)(hb_ >> 16);                                      \
        am[j] = (short)(mb_ >> 16);                                      \
        al[j] = (short)(lb_ >> 16);                                      \
    } }

// products {hh, hm, hl, mh, mm, lh}; two independent acc chains
#define COMPUTE(p_) {                                                    \
    s16x8 bh_ = __builtin_bit_cast(s16x8, wset##p_[0]);                  \
    s16x8 bm_ = __builtin_bit_cast(s16x8, wset##p_[1]);                  \
    s16x8 bl_ = __builtin_bit_cast(s16x8, wset##p_[2]);                  \
    acc0 = __builtin_amdgcn_mfma_f32_16x16x32_bf16(ah, bh_, acc0, 0, 0, 0); \
    acc1 = __builtin_amdgcn_mfma_f32_16x16x32_bf16(am, bh_, acc1, 0, 0, 0); \
    acc0 = __builtin_amdgcn_mfma_f32_16x16x32_bf16(ah, bm_, acc0, 0, 0, 0); \
    acc1 = __builtin_amdgcn_mfma_f32_16x16x32_bf16(am, bm_, acc1, 0, 0, 0); \
    acc0 = __builtin_amdgcn_mfma_f32_16x16x32_bf16(ah, bl_, acc0, 0, 0, 0); \
    acc1 = __builtin_amdgcn_mfma_f32_16x16x32_bf16(al, bh_, acc1, 0, 0, 0); \
    }

__global__ __launch_bounds__(256, 4) void router_main(
    const float* __restrict__ x, const uint4* __restrict__ wq,
    float* __restrict__ out)
{
    // LDS only for the epilogue (~4.6 KB) -> 4 blocks/CU, no K-loop barriers
    __shared__ float lg[TB][NEXP + 1];
    __shared__ float m1s[TB], rss[TB];
    __shared__ float s_ent, s_conf, s_cnt[NEXP];

    const int tid = threadIdx.x;
    const int l   = tid & 63;
    const int wv  = __builtin_amdgcn_readfirstlane(tid >> 6); // ntile (SGPR)
    const int qd  = l >> 4;
    const int t0  = blockIdx.x * TB;

    if (tid == 0) { s_ent = 0.0f; s_conf = 0.0f; }
    if (tid < NEXP) s_cnt[tid] = 0.0f;

    // A-fragment source: token t0 + (l&15), k = 32c + 8*qd + j
    const float4* xq = (const float4*)(x + (size_t)(t0 + (l & 15)) * DIM);

    f32x4 acc0 = (f32x4)(0.0f), acc1 = (f32x4)(0.0f);
    s16x8 ah, am, al;
    float4 xset0[2], xset1[2];
    uint4  wset0[3], wset1[3];

    LOADX(0, 0); LOADX(1, 1);
    LOADW(0, 0); LOADW(1, 1);

    for (int c = 0; c < NSTAGE; c += 2) {
        CONVX(0);
        if (c + 2 < NSTAGE) LOADX(0, c + 2);
        COMPUTE(0);
        if (c + 2 < NSTAGE) LOADW(0, c + 2);
        CONVX(1);
        if (c + 3 < NSTAGE) LOADX(1, c + 3);
        COMPUTE(1);
        if (c + 3 < NSTAGE) LOADW(1, c + 3);
    }

    // C/D layout (verified): col = lane&15 (expert), row = qd*4 + r (token)
    #pragma unroll
    for (int r = 0; r < 4; ++r)
        lg[4 * qd + r][16 * wv + (l & 15)] = acc0[r] + acc1[r];
    __syncthreads();

    // 16 threads: top-2 + softmax stats per token
    if (tid < TB) {
        const int t = tid;
        float m1 = -INFINITY, m2 = -INFINITY;
        int i1 = 0, i2 = 0;
        for (int e = 0; e < NEXP; ++e) {
            float lv = lg[t][e];
            if (lv > m1)      { m2 = m1; i2 = i1; m1 = lv; i1 = e; }
            else if (lv > m2) { m2 = lv; i2 = e; }
        }
        float ssum = 0.0f, tsum = 0.0f;
        for (int e = 0; e < NEXP; ++e) {
            float d = lg[t][e] - m1;
            float ex = __expf(d);
            ssum += ex;
            tsum += d * ex;
        }
        float rs = 1.0f / ssum;
        float H  = logf(ssum) - tsum * rs;   // H = ln(s) - (sum d e^d)/s
        float e2 = __expf(m2 - m1);
        float rn = 1.0f / (1.0f + e2);
        float w0 = rn, w1v = e2 * rn;
        m1s[t] = m1; rss[t] = rs;

        *(float2*)&out[OFF_W + 2 * (t0 + t)] = make_float2(w0, w1v);
        *(float2*)&out[OFF_I + 2 * (t0 + t)] = make_float2((float)i1, (float)i2);

        atomicAdd(&s_ent,  H);
        atomicAdd(&s_conf, w0);
        atomicAdd(&s_cnt[i1], 1.0f);
        atomicAdd(&s_cnt[i2], 1.0f);
    }
    __syncthreads();

    // coalesced probs write: 256 float4s / 256 threads
    {
        int t  = tid >> 4;
        int qq = tid & 15;
        float m  = m1s[t];
        float rs = rss[t];
        float4 pr;
        pr.x = __expf(lg[t][4 * qq + 0] - m) * rs;
        pr.y = __expf(lg[t][4 * qq + 1] - m) * rs;
        pr.z = __expf(lg[t][4 * qq + 2] - m) * rs;
        pr.w = __expf(lg[t][4 * qq + 3] - m) * rs;
        *(float4*)&out[OFF_P + (size_t)(t0 + t) * NEXP + 4 * qq] = pr;
    }

    // stats: pre-scaled so the atomic sums are exact / final means
    if (tid == 0) {
        atomicAdd(&out[OFF_ENT],  s_ent  * (1.0f / 16384.0f));
        atomicAdd(&out[OFF_CONF], s_conf * (1.0f / 16384.0f));
    }
    if (tid < NEXP)
        atomicAdd(&out[OFF_UTIL + tid], s_cnt[tid] * (1.0f / 32768.0f));
}

extern "C" void kernel_launch(void* const* d_in, const int* in_sizes, int n_in,
                              void* d_out, int out_size, void* d_ws, size_t ws_size,
                              hipStream_t stream) {
    const float* x  = (const float*)d_in[0];
    const float* Wg = (const float*)d_in[1];
    float* out = (float*)d_out;
    (void)in_sizes; (void)n_in; (void)out_size; (void)ws_size;

    router_init<<<dim3(1), dim3(128), 0, stream>>>(out);
    router_wsplit<<<dim3(NSTAGE), dim3(256), 0, stream>>>(Wg, (uint4*)d_ws);
    router_main<<<dim3(NTOK / TB), dim3(256), 0, stream>>>(x, (const uint4*)d_ws, out);
}

// Round 6
// 240.291 us; speedup vs baseline: 1.1705x; 1.1705x over previous
//
#include <hip/hip_runtime.h>
#include <math.h>

#define NTOK 16384
#define DIM 2048
#define NEXP 64
#define TB 32              // tokens per block (2 MFMA token-tiles)
#define NSTAGE 64          // K chunks of 32

// flat output offsets (return order)
#define OFF_W    0
#define OFF_I    32768
#define OFF_P    65536
#define OFF_ENT  1114112
#define OFF_CONF 1114113
#define OFF_UTIL 1114114

typedef short s16x8 __attribute__((ext_vector_type(8)));
typedef float f32x4 __attribute__((ext_vector_type(4)));

__device__ __forceinline__ unsigned short f2bf(float v) {
    unsigned u = __builtin_bit_cast(unsigned, v);
    u = u + 0x7FFFu + ((u >> 16) & 1u);          // RNE
    return (unsigned short)(u >> 16);
}
__device__ __forceinline__ float bf2f(unsigned short b) {
    return __builtin_bit_cast(float, (unsigned)b << 16);
}

__global__ void router_init(float* __restrict__ out) {
    int tid = threadIdx.x;
    if (tid < 66) out[OFF_ENT + tid] = 0.0f;
}

// Split W into 3 bf16 planes (hi/mid/lo), fragment-linear (verified r4/r5):
// plane p, chunk c, ntile nt, lane l -> uint4 at wsp[p*16384 + c*256 + nt*64 + l]
// fragment element j: W[16nt + (l&15)][32c + 8*(l>>4) + j]
__global__ void router_wsplit(const float* __restrict__ Wg, uint4* __restrict__ wsp) {
    const int c = blockIdx.x;
    const int t = threadIdx.x;
    const int nt = t >> 6, l = t & 63;
    const int e  = 16 * nt + (l & 15);
    const int k0 = 32 * c + 8 * (l >> 4);
    const float* src = Wg + (size_t)e * DIM + k0;
    float4 a = *(const float4*)src;
    float4 b = *(const float4*)(src + 4);
    float v[8] = {a.x, a.y, a.z, a.w, b.x, b.y, b.z, b.w};
    unsigned short H[8], M[8], L[8];
    #pragma unroll
    for (int j = 0; j < 8; ++j) {
        H[j] = f2bf(v[j]);  float r = v[j] - bf2f(H[j]);
        M[j] = f2bf(r);     r = r - bf2f(M[j]);
        L[j] = f2bf(r);
    }
    uint4 ph, pm, pl;
    ph.x = H[0] | ((unsigned)H[1] << 16); ph.y = H[2] | ((unsigned)H[3] << 16);
    ph.z = H[4] | ((unsigned)H[5] << 16); ph.w = H[6] | ((unsigned)H[7] << 16);
    pm.x = M[0] | ((unsigned)M[1] << 16); pm.y = M[2] | ((unsigned)M[3] << 16);
    pm.z = M[4] | ((unsigned)M[5] << 16); pm.w = M[6] | ((unsigned)M[7] << 16);
    pl.x = L[0] | ((unsigned)L[1] << 16); pl.y = L[2] | ((unsigned)L[3] << 16);
    pl.z = L[4] | ((unsigned)L[5] << 16); pl.w = L[6] | ((unsigned)L[7] << 16);
    const int idx = c * 256 + t;
    wsp[idx]         = ph;
    wsp[16384 + idx] = pm;
    wsp[32768 + idx] = pl;
}

// W regs: 2 ntiles (2np, 2np+1) x 3 planes {hi,mid,lo}
#define LOADW(W_, c_) { const int b_ = (c_)*256 + np*128 + l;  \
    W_[0] = wq[b_];          W_[1] = wq[b_ + 64];              \
    W_[2] = wq[16384 + b_];  W_[3] = wq[16384 + b_ + 64];      \
    W_[4] = wq[32768 + b_];  W_[5] = wq[32768 + b_ + 64]; }

// exact truncation split of 8 fp32 -> 3 bf16 planes
#define CONVA(a0_, a1_) {                                                \
    float xv[8];                                                         \
    xv[0]=a0_.x; xv[1]=a0_.y; xv[2]=a0_.z; xv[3]=a0_.w;                  \
    xv[4]=a1_.x; xv[5]=a1_.y; xv[6]=a1_.z; xv[7]=a1_.w;                  \
    _Pragma("unroll")                                                    \
    for (int j = 0; j < 8; ++j) {                                        \
        unsigned u_  = __builtin_bit_cast(unsigned, xv[j]);              \
        unsigned hb_ = u_ & 0xFFFF0000u;                                 \
        float    r_  = xv[j] - __builtin_bit_cast(float, hb_);           \
        unsigned mb_ = __builtin_bit_cast(unsigned, r_) & 0xFFFF0000u;   \
        float    r2_ = r_ - __builtin_bit_cast(float, mb_);              \
        unsigned lb_ = __builtin_bit_cast(unsigned, r2_);                \
        ah[j] = (short)(hb_ >> 16);                                      \
        am[j] = (short)(mb_ >> 16);                                      \
        al[j] = (short)(lb_ >> 16);                                      \
    } }

// 6-product split per tile {hh,mh,hm,mm,hl,lh}; two tiles interleaved for ILP
#define COMPUTE(W_) {                                                    \
    s16x8 b0h_ = __builtin_bit_cast(s16x8, W_[0]);                       \
    s16x8 b1h_ = __builtin_bit_cast(s16x8, W_[1]);                       \
    s16x8 b0m_ = __builtin_bit_cast(s16x8, W_[2]);                       \
    s16x8 b1m_ = __builtin_bit_cast(s16x8, W_[3]);                       \
    s16x8 b0l_ = __builtin_bit_cast(s16x8, W_[4]);                       \
    s16x8 b1l_ = __builtin_bit_cast(s16x8, W_[5]);                       \
    acc0 = __builtin_amdgcn_mfma_f32_16x16x32_bf16(ah, b0h_, acc0, 0, 0, 0); \
    acc1 = __builtin_amdgcn_mfma_f32_16x16x32_bf16(ah, b1h_, acc1, 0, 0, 0); \
    acc0 = __builtin_amdgcn_mfma_f32_16x16x32_bf16(am, b0h_, acc0, 0, 0, 0); \
    acc1 = __builtin_amdgcn_mfma_f32_16x16x32_bf16(am, b1h_, acc1, 0, 0, 0); \
    acc0 = __builtin_amdgcn_mfma_f32_16x16x32_bf16(ah, b0m_, acc0, 0, 0, 0); \
    acc1 = __builtin_amdgcn_mfma_f32_16x16x32_bf16(ah, b1m_, acc1, 0, 0, 0); \
    acc0 = __builtin_amdgcn_mfma_f32_16x16x32_bf16(am, b0m_, acc0, 0, 0, 0); \
    acc1 = __builtin_amdgcn_mfma_f32_16x16x32_bf16(am, b1m_, acc1, 0, 0, 0); \
    acc0 = __builtin_amdgcn_mfma_f32_16x16x32_bf16(ah, b0l_, acc0, 0, 0, 0); \
    acc1 = __builtin_amdgcn_mfma_f32_16x16x32_bf16(ah, b1l_, acc1, 0, 0, 0); \
    acc0 = __builtin_amdgcn_mfma_f32_16x16x32_bf16(al, b0h_, acc0, 0, 0, 0); \
    acc1 = __builtin_amdgcn_mfma_f32_16x16x32_bf16(al, b1h_, acc1, 0, 0, 0); \
    }

// Read the lane's A fragment (8 fp32) for chunk slot (buf,cc) + convert.
// XOR swizzle: LDS slot s of token t holds global granule kq = s ^ (t&7).
#define READA(buf_, cc_) {                                               \
    const int sl0_ = (2*qd)     ^ (tl & 7);                              \
    const int sl1_ = (2*qd + 1) ^ (tl & 7);                              \
    float4 a0_ = *(const float4*)&Xs[buf_][cc_][tl][4*sl0_];             \
    float4 a1_ = *(const float4*)&Xs[buf_][cc_][tl][4*sl1_];             \
    CONVA(a0_, a1_);                                                     \
    }

__global__ __launch_bounds__(256, 2) void router_main(
    const float* __restrict__ x, const uint4* __restrict__ wq,
    float* __restrict__ out)
{
    // x staging: [buf][chunk-of-2][token][8 granules x 4 floats], XOR-swizzled. 16 KB
    __shared__ __align__(16) float Xs[2][2][TB][32];
    __shared__ float lg[TB][NEXP + 1];
    __shared__ float m1s[TB], rss[TB];
    __shared__ float s_ent, s_conf, s_cnt[NEXP];

    const int tid = threadIdx.x;
    const int l   = tid & 63;
    const int w   = tid >> 6;
    const int np  = __builtin_amdgcn_readfirstlane(w >> 1); // expert-pair (SGPR)
    const int tt  = w & 1;                                  // token-tile
    const int qd  = l >> 4;
    const int tl  = tt * 16 + (l & 15);                     // local token
    const int t0  = blockIdx.x * TB;

    if (tid == 0) { s_ent = 0.0f; s_conf = 0.0f; }
    if (tid < NEXP) s_cnt[tid] = 0.0f;

    // staging: thread i -> token i>>3, LDS slot i&7, global granule (i&7)^(t&7)
    const int st  = tid >> 3;
    const int sq  = tid & 7;
    const int gkq = sq ^ (st & 7);
    const float* xsrc = x + (size_t)(t0 + st) * DIM + 4 * gkq; // + 32*c floats

    f32x4 acc0 = (f32x4)(0.0f), acc1 = (f32x4)(0.0f);
    s16x8 ah, am, al;
    uint4 wA[6], wB[6];
    float4 xr0, xr1;

    // prologue: chunks 0,1 -> Xs[0]; xr <- chunks 2,3; W chunks 0,1
    xr0 = *(const float4*)(xsrc);
    xr1 = *(const float4*)(xsrc + 32);
    LOADW(wA, 0); LOADW(wB, 1);
    *(float4*)&Xs[0][0][st][4 * sq] = xr0;
    *(float4*)&Xs[0][1][st][4 * sq] = xr1;
    xr0 = *(const float4*)(xsrc + 64);
    xr1 = *(const float4*)(xsrc + 96);
    __syncthreads();

    for (int s = 0; s < NSTAGE; s += 2) {
        const int buf = (s >> 1) & 1;
        // stage chunks s+2,s+3 into the other buffer (data prefetched last body)
        if (s + 2 < NSTAGE) {
            *(float4*)&Xs[buf ^ 1][0][st][4 * sq] = xr0;
            *(float4*)&Xs[buf ^ 1][1][st][4 * sq] = xr1;
        }
        // prefetch chunks s+4,s+5 (consumed 2 barriers from now -> latency-safe)
        if (s + 4 < NSTAGE) {
            xr0 = *(const float4*)(xsrc + (s + 4) * 32);
            xr1 = *(const float4*)(xsrc + (s + 5) * 32);
        }
        // chunk s
        READA(buf, 0);
        COMPUTE(wA);
        if (s + 2 < NSTAGE) LOADW(wA, s + 2);
        // chunk s+1
        READA(buf, 1);
        COMPUTE(wB);
        if (s + 3 < NSTAGE) LOADW(wB, s + 3);
        __syncthreads();
    }

    // C/D layout (verified): col = lane&15 (expert), row = qd*4 + r (token)
    #pragma unroll
    for (int r = 0; r < 4; ++r) {
        lg[tt * 16 + 4 * qd + r][np * 32 + (l & 15)]      = acc0[r];
        lg[tt * 16 + 4 * qd + r][np * 32 + 16 + (l & 15)] = acc1[r];
    }
    __syncthreads();

    // 32 threads: top-2 + softmax stats per token
    if (tid < TB) {
        const int t = tid;
        float m1 = -INFINITY, m2 = -INFINITY;
        int i1 = 0, i2 = 0;
        for (int e = 0; e < NEXP; ++e) {
            float lv = lg[t][e];
            if (lv > m1)      { m2 = m1; i2 = i1; m1 = lv; i1 = e; }
            else if (lv > m2) { m2 = lv; i2 = e; }
        }
        float ssum = 0.0f, tsum = 0.0f;
        for (int e = 0; e < NEXP; ++e) {
            float d = lg[t][e] - m1;
            float ex = __expf(d);
            ssum += ex;
            tsum += d * ex;
        }
        float rs = 1.0f / ssum;
        float H  = logf(ssum) - tsum * rs;   // H = ln(s) - (sum d e^d)/s
        float e2 = __expf(m2 - m1);
        float rn = 1.0f / (1.0f + e2);
        float w0 = rn, w1v = e2 * rn;
        m1s[t] = m1; rss[t] = rs;

        *(float2*)&out[OFF_W + 2 * (t0 + t)] = make_float2(w0, w1v);
        *(float2*)&out[OFF_I + 2 * (t0 + t)] = make_float2((float)i1, (float)i2);

        atomicAdd(&s_ent,  H);
        atomicAdd(&s_conf, w0);
        atomicAdd(&s_cnt[i1], 1.0f);
        atomicAdd(&s_cnt[i2], 1.0f);
    }
    __syncthreads();

    // coalesced probs write: 512 float4s / 256 threads
    #pragma unroll
    for (int p = 0; p < 2; ++p) {
        int Q  = tid + 256 * p;
        int t  = Q >> 4;
        int qq = Q & 15;
        float m  = m1s[t];
        float rs = rss[t];
        float4 pr;
        pr.x = __expf(lg[t][4 * qq + 0] - m) * rs;
        pr.y = __expf(lg[t][4 * qq + 1] - m) * rs;
        pr.z = __expf(lg[t][4 * qq + 2] - m) * rs;
        pr.w = __expf(lg[t][4 * qq + 3] - m) * rs;
        *(float4*)&out[OFF_P + (size_t)(t0 + t) * NEXP + 4 * qq] = pr;
    }

    // stats: pre-scaled so the atomic sums are exact / final means
    if (tid == 0) {
        atomicAdd(&out[OFF_ENT],  s_ent  * (1.0f / 16384.0f));
        atomicAdd(&out[OFF_CONF], s_conf * (1.0f / 16384.0f));
    }
    if (tid < NEXP)
        atomicAdd(&out[OFF_UTIL + tid], s_cnt[tid] * (1.0f / 32768.0f));
}

extern "C" void kernel_launch(void* const* d_in, const int* in_sizes, int n_in,
                              void* d_out, int out_size, void* d_ws, size_t ws_size,
                              hipStream_t stream) {
    const float* x  = (const float*)d_in[0];
    const float* Wg = (const float*)d_in[1];
    float* out = (float*)d_out;
    (void)in_sizes; (void)n_in; (void)out_size; (void)ws_size;

    router_init<<<dim3(1), dim3(128), 0, stream>>>(out);
    router_wsplit<<<dim3(NSTAGE), dim3(256), 0, stream>>>(Wg, (uint4*)d_ws);
    router_main<<<dim3(NTOK / TB), dim3(256), 0, stream>>>(x, (const uint4*)d_ws, out);
}